// Round 1
// baseline (734.604 us; speedup 1.0000x reference)
//
#include <hip/hip_runtime.h>

#define CIN 96
#define COUT 192
#define SW 4
#define BM 128       // windows per block
#define KPA 96       // A row stride (shorts); unpadded (conflicts only on 6 cold reads/wave)
#define KPW 104      // Wt row stride (shorts); 16B-multiple, conflict-light for hot B-frag reads

typedef __attribute__((ext_vector_type(8))) short bf16x8;
typedef __attribute__((ext_vector_type(4))) float f32x4;

// fp32 -> bf16 round-to-nearest-even, bit pattern in a short
__device__ __forceinline__ short f2bf(float x) {
  unsigned int u;
  __builtin_memcpy(&u, &x, 4);
  u += 0x7fffu + ((u >> 16) & 1u);
  return (short)(u >> 16);
}

// Fused: windowed mean pool (stride 4) + bf16-MFMA GEMM (M,96)x(96,192) + bias + ReLU
// + coord/scores/batch pooled outputs + lengths_down/offset_down.
//
// __launch_bounds__(256,2): occupancy is LDS-capped at 2 blocks/CU (=2 waves/SIMD),
// so let the register allocator use the full ~256-reg budget for deep load pipelining.
__global__ __launch_bounds__(256, 2) void fused_kernel(
    const float* __restrict__ feat, const float* __restrict__ coord,
    const float* __restrict__ scores, const float* __restrict__ W,
    const float* __restrict__ bias, const int* __restrict__ lengths, int B,
    float* __restrict__ out) {
  __shared__ short A_lds[BM * KPA];     // 24576 B, bf16 pooled A tile
  __shared__ short Wt_lds[COUT * KPW];  // 39936 B, bf16 W transposed [n][k]
  __shared__ int s_meta[BM];            // start | (cnt<<28); total LDS = 65024 B

  const int tid = threadIdx.x;
  const long long m0 = (long long)blockIdx.x * BM;

  // Total window count M (wave-uniform scalar loop over B<=8 lengths).
  long long M = 0;
  for (int i = 0; i < B; ++i) M += ((long long)lengths[i] + (SW - 1)) >> 2;

  // Per-window metadata for this block's 128 windows.
  long long startL = 0; int cntL = 0, bfL = 0;
  if (tid < BM) {
    long long m = m0 + tid;
    long long off = 0, woff = 0;
    for (int i = 0; i < B; ++i) {
      long long L = lengths[i];
      long long nw = (L + (SW - 1)) >> 2;
      if (m >= woff && m < woff + nw) {
        long long st = off + (m - woff) * SW;
        long long rem = off + L - st;
        startL = st;
        cntL = (int)(rem < (long long)SW ? rem : (long long)SW);
        bfL = i;
      }
      off += L; woff += nw;
    }
    s_meta[tid] = (int)startL | (cntL << 28);  // start < 2^28 here
  }
  __syncthreads();

  // --- Stage pooled A tile (fp32 accumulate, one bf16 round) ---
  // 128 windows x 24 float4 groups = 3072 tasks, 12/thread; coalesced.
  // BRANCHLESS: always load 4 rows (compile-time count) and mask the tail.
  // Safe: every valid window's start satisfies st+3 <= N-1 (last window of the
  // last batch is full: L[B-1] % 4 == 0), and invalid windows have st == 0.
  // cw < 4 only for ~1 window per batch (7 of 262k) -> masks are nearly free,
  // and all 16 loads per unroll group are independent -> deep VMEM pipelining.
  #pragma unroll 4
  for (int i = 0; i < 12; ++i) {
    int task = tid + 256 * i;
    int w = task / 24;
    int g = task - w * 24;
    int mv = s_meta[w];
    int cw = (int)((unsigned)mv >> 28);
    int st = mv & 0x0FFFFFFF;
    const float* fp = feat + (long long)st * CIN + g * 4;
    float4 v0 = *(const float4*)(fp);
    float4 v1 = *(const float4*)(fp + CIN);
    float4 v2 = *(const float4*)(fp + 2 * CIN);
    float4 v3 = *(const float4*)(fp + 3 * CIN);
    const float4 z4 = {0.f, 0.f, 0.f, 0.f};
    v0 = (cw > 0) ? v0 : z4;
    v1 = (cw > 1) ? v1 : z4;
    v2 = (cw > 2) ? v2 : z4;
    v3 = (cw > 3) ? v3 : z4;
    float sx = (v0.x + v1.x) + (v2.x + v3.x);
    float sy = (v0.y + v1.y) + (v2.y + v3.y);
    float sz = (v0.z + v1.z) + (v2.z + v3.z);
    float sw2 = (v0.w + v1.w) + (v2.w + v3.w);
    float inv = cw ? 1.0f / (float)cw : 0.f;
    short4 h;
    h.x = f2bf(sx * inv); h.y = f2bf(sy * inv);
    h.z = f2bf(sz * inv); h.w = f2bf(sw2 * inv);
    *(short4*)&A_lds[w * KPA + g * 4] = h;
  }

  // --- Stage W transposed to bf16: Wt[n][k], n=0..191, k=0..95 ---
  // 192 cols x 12 k-groups(8) = 2304 tasks, 9/thread; global reads coalesced over n.
  #pragma unroll 3
  for (int i = 0; i < 9; ++i) {
    int task = tid + 256 * i;
    int kg = task / COUT;
    int n = task - kg * COUT;
    const float* wp = W + kg * 8 * COUT + n;
    bf16x8 hv;
    #pragma unroll
    for (int j = 0; j < 8; ++j) hv[j] = f2bf(wp[j * COUT]);
    *(bf16x8*)&Wt_lds[n * KPW + kg * 8] = hv;   // byte addr n*208+kg*16, 16B aligned
  }

  // --- Small pooled outputs (independent of LDS; threads 0..127) ---
  // Branchless 4-row load + masked accumulate (same safety argument as A tile).
  if (tid < BM) {
    long long m = m0 + tid;
    if (m < M) {
      const float* cp = coord + startL * 3;
      const float* sp = scores + startL;
      float cx = 0.f, cy = 0.f, cz = 0.f, ss = 0.f;
      #pragma unroll
      for (int p = 0; p < 4; ++p) {
        float x = cp[p * 3 + 0];
        float y = cp[p * 3 + 1];
        float zz = cp[p * 3 + 2];
        float sv = sp[p];
        float mk = (p < cntL) ? 1.f : 0.f;
        cx = fmaf(mk, x, cx);
        cy = fmaf(mk, y, cy);
        cz = fmaf(mk, zz, cz);
        ss = fmaf(mk, sv, ss);
      }
      float inv = 1.0f / (float)cntL;
      long long o1 = M * (long long)COUT;
      long long o2 = o1 + M * 3;
      long long o3 = o2 + M;
      out[o1 + m * 3 + 0] = cx * inv;
      out[o1 + m * 3 + 1] = cy * inv;
      out[o1 + m * 3 + 2] = cz * inv;
      out[o2 + m] = (float)bfL;   // batch id, exact in fp32
      out[o3 + m] = ss * inv;
    }
  }
  if (blockIdx.x == 0 && tid == 0) {
    long long o4 = M * (long long)(COUT + 3 + 1 + 1);
    long long cum = 0;
    for (int i = 0; i < B; ++i) {
      long long nw = ((long long)lengths[i] + (SW - 1)) >> 2;
      out[o4 + i] = (float)nw;
      cum += nw;
      out[o4 + B + i] = (float)cum;
    }
  }

  __syncthreads();

  // --- MFMA phase: no further barriers ---
  const int wv = tid >> 6;      // wave 0..3 -> rows wv*32 .. wv*32+31
  const int lane = tid & 63;
  const int lm = lane & 15;
  const int quad = lane >> 4;

  // A-fragments in registers: 2 m-tiles x 3 k-steps. Layout A[m=lane&15][k=quad*8+j].
  bf16x8 af[2][3];
  #pragma unroll
  for (int mt = 0; mt < 2; ++mt)
    #pragma unroll
    for (int ks = 0; ks < 3; ++ks)
      af[mt][ks] = *(const bf16x8*)&A_lds[(wv * 32 + mt * 16 + lm) * KPA + ks * 32 + quad * 8];

  f32x4 acc[2][12];
  #pragma unroll
  for (int mt = 0; mt < 2; ++mt)
    #pragma unroll
    for (int nt = 0; nt < 12; ++nt)
      acc[mt][nt] = (f32x4){0.f, 0.f, 0.f, 0.f};

  #pragma unroll
  for (int nt = 0; nt < 12; ++nt) {
    const int nrow = nt * 16 + lm;   // B-fragment: col n = lane&15, k = quad*8+j
    #pragma unroll
    for (int ks = 0; ks < 3; ++ks) {
      bf16x8 bfr = *(const bf16x8*)&Wt_lds[nrow * KPW + ks * 32 + quad * 8];
      acc[0][nt] = __builtin_amdgcn_mfma_f32_16x16x32_bf16(af[0][ks], bfr, acc[0][nt], 0, 0, 0);
      acc[1][nt] = __builtin_amdgcn_mfma_f32_16x16x32_bf16(af[1][ks], bfr, acc[1][nt], 0, 0, 0);
    }
  }

  // --- Epilogue: bias + ReLU. C/D layout: col=lane&15, row=quad*4+reg ---
  #pragma unroll
  for (int nt = 0; nt < 12; ++nt) {
    int col = nt * 16 + lm;
    float bv = bias[col];
    #pragma unroll
    for (int mt = 0; mt < 2; ++mt) {
      long long rbase = m0 + wv * 32 + mt * 16 + quad * 4;
      #pragma unroll
      for (int r = 0; r < 4; ++r) {
        long long m = rbase + r;
        if (m < M) {
          float x = acc[mt][nt][r] + bv;
          out[m * COUT + col] = x > 0.f ? x : 0.f;
        }
      }
    }
  }
}

extern "C" void kernel_launch(void* const* d_in, const int* in_sizes, int n_in,
                              void* d_out, int out_size, void* d_ws, size_t ws_size,
                              hipStream_t stream) {
  const float* feat    = (const float*)d_in[0];
  const float* coord   = (const float*)d_in[1];
  const float* scores  = (const float*)d_in[2];
  const float* W       = (const float*)d_in[3];
  const float* bias    = (const float*)d_in[4];
  const int*   lengths = (const int*)d_in[5];
  float* out = (float*)d_out;

  const int N = in_sizes[2];   // number of points (scores is (N,))
  const int B = in_sizes[5];   // number of batches
  const int Mmax = N / SW + B; // data-independent upper bound on window count

  const int blocks = (Mmax + BM - 1) / BM;
  fused_kernel<<<blocks, 256, 0, stream>>>(feat, coord, scores, W, bias, lengths, B, out);
}

// Round 2
// 651.839 us; speedup vs baseline: 1.1270x; 1.1270x over previous
//
#include <hip/hip_runtime.h>

#define CIN 96
#define COUT 192
#define SW 4
#define BM 128        // rows (windows) per GEMM block
#define KPA 96        // fallback A row stride (shorts)
#define KPW 104       // Wt row stride (shorts); 16B-multiple, conflict-light
#define TPB_A 256
#define TPT_A 8       // tasks per thread in pool kernel
#define TPB_B 512

typedef __attribute__((ext_vector_type(8))) short bf16x8;
typedef __attribute__((ext_vector_type(4))) float f32x4;

// fp32 -> bf16 round-to-nearest-even, bit pattern in a short
__device__ __forceinline__ short f2bf(float x) {
  unsigned int u;
  __builtin_memcpy(&u, &x, 4);
  u += 0x7fffu + ((u >> 16) & 1u);
  return (short)(u >> 16);
}

// ---------------------------------------------------------------------------
// Kernel A: pure streaming. No LDS, no barriers, high occupancy.
// Task ranges (t = global task id):
//   [0, M*24)        : pooled A tile. w = t/24, g = t%24: mean of 4 rows'
//                      float4 group g -> bf16 short4 into wsA[w][g*4..+4).
//   [M*24, M*25)     : coord/scores/batch pooled outputs for window m.
//   [M*25, M*25+2304): W transpose -> bf16 Wt[n][k] (KPW-padded) into wsWt.
// Plus lengths_down/offset_down written by block 0 thread 0.
// ---------------------------------------------------------------------------
__global__ __launch_bounds__(TPB_A) void pool_kernel(
    const float* __restrict__ feat, const float* __restrict__ coord,
    const float* __restrict__ scores, const float* __restrict__ W,
    const int* __restrict__ lengths, int B,
    short* __restrict__ wsA, short* __restrict__ wsWt,
    float* __restrict__ out) {
  // Window count M (uniform; lengths is tiny and L1-hot).
  int M = 0;
  for (int i = 0; i < B; ++i) M += (lengths[i] + (SW - 1)) >> 2;
  const int R0 = M * 24;
  const int R1 = R0 + M;
  const int R2 = R1 + COUT * 12;  // 2304 W-transpose tasks

  const int base = blockIdx.x * (TPB_A * TPT_A) + threadIdx.x;

  #pragma unroll
  for (int u = 0; u < TPT_A; ++u) {
    const int t = base + u * TPB_A;
    if (t < R0) {
      // ---- pooled A ----
      const int w = t / 24;
      const int g = t - w * 24;
      // scan batches for window w -> start row st, count cw
      int off = 0, woff = 0, st = 0, cw = 0;
      for (int i = 0; i < B; ++i) {
        const int L = lengths[i];
        const int nw = (L + (SW - 1)) >> 2;
        if (w >= woff && w < woff + nw) {
          st = off + (w - woff) * SW;
          const int rem = off + L - st;
          cw = rem < SW ? rem : SW;
        }
        off += L; woff += nw;
      }
      const float* fp = feat + (long long)st * CIN + g * 4;
      // Unconditional 4-row load (always in-bounds: last window of the last
      // batch is full), mask the tail rows of short windows by multiply.
      float4 v0 = *(const float4*)(fp);
      float4 v1 = *(const float4*)(fp + CIN);
      float4 v2 = *(const float4*)(fp + 2 * CIN);
      float4 v3 = *(const float4*)(fp + 3 * CIN);
      const float k1 = (cw > 1) ? 1.f : 0.f;
      const float k2 = (cw > 2) ? 1.f : 0.f;
      const float k3 = (cw > 3) ? 1.f : 0.f;
      float sx = v0.x + k1 * v1.x + k2 * v2.x + k3 * v3.x;
      float sy = v0.y + k1 * v1.y + k2 * v2.y + k3 * v3.y;
      float sz = v0.z + k1 * v1.z + k2 * v2.z + k3 * v3.z;
      float sw2 = v0.w + k1 * v1.w + k2 * v2.w + k3 * v3.w;
      const float inv = 1.0f / (float)cw;
      short4 h;
      h.x = f2bf(sx * inv); h.y = f2bf(sy * inv);
      h.z = f2bf(sz * inv); h.w = f2bf(sw2 * inv);
      *(short4*)&wsA[(long long)w * CIN + g * 4] = h;
    } else if (t < R1) {
      // ---- coord / scores / batch pooled outputs ----
      const int m = t - R0;
      int off = 0, woff = 0, st = 0, cw = 0, bf = 0;
      for (int i = 0; i < B; ++i) {
        const int L = lengths[i];
        const int nw = (L + (SW - 1)) >> 2;
        if (m >= woff && m < woff + nw) {
          st = off + (m - woff) * SW;
          const int rem = off + L - st;
          cw = rem < SW ? rem : SW;
          bf = i;
        }
        off += L; woff += nw;
      }
      const float* cp = coord + (long long)st * 3;
      const float* sp = scores + st;
      float cx = 0.f, cy = 0.f, cz = 0.f, ss = 0.f;
      #pragma unroll
      for (int p = 0; p < 4; ++p) {
        const float mk = (p < cw) ? 1.f : 0.f;
        cx = fmaf(mk, cp[p * 3 + 0], cx);
        cy = fmaf(mk, cp[p * 3 + 1], cy);
        cz = fmaf(mk, cp[p * 3 + 2], cz);
        ss = fmaf(mk, sp[p], ss);
      }
      const float inv = 1.0f / (float)cw;
      const long long o1 = (long long)M * COUT;
      const long long o2 = o1 + (long long)M * 3;
      const long long o3 = o2 + M;
      out[o1 + (long long)m * 3 + 0] = cx * inv;
      out[o1 + (long long)m * 3 + 1] = cy * inv;
      out[o1 + (long long)m * 3 + 2] = cz * inv;
      out[o2 + m] = (float)bf;
      out[o3 + m] = ss * inv;
    } else if (t < R2) {
      // ---- W transpose -> bf16 Wt[n][k], KPW-padded rows ----
      const int j = t - R1;
      const int kg = j / COUT;
      const int n = j - kg * COUT;
      const float* wp = W + (long long)kg * 8 * COUT + n;
      bf16x8 hv;
      #pragma unroll
      for (int q = 0; q < 8; ++q) hv[q] = f2bf(wp[q * COUT]);
      *(bf16x8*)&wsWt[n * KPW + kg * 8] = hv;  // byte n*208+kg*16, 16B aligned
    }
  }

  if (blockIdx.x == 0 && threadIdx.x == 0) {
    const long long o4 = (long long)M * (COUT + 3 + 1 + 1);
    long long cum = 0;
    for (int i = 0; i < B; ++i) {
      const long long nw = ((long long)lengths[i] + (SW - 1)) >> 2;
      out[o4 + i] = (float)nw;
      cum += nw;
      out[o4 + B + i] = (float)cum;
    }
  }
}

// ---------------------------------------------------------------------------
// Kernel B: lean GEMM. 512 threads = 8 waves, each wave owns 16 rows x 192
// cols (acc = 12 f32x4 = 48 regs). Only Wt lives in LDS (39936 B -> up to
// 4 blocks/CU by LDS). A-fragments are loaded global->reg BEFORE the barrier
// so the HBM latency hides under the Wt staging.
// ---------------------------------------------------------------------------
__global__ __launch_bounds__(TPB_B) void gemm_kernel(
    const short* __restrict__ wsA, const short* __restrict__ wsWt,
    const float* __restrict__ bias, const int* __restrict__ lengths, int B,
    float* __restrict__ out) {
  __shared__ alignas(16) short Wt_lds[COUT * KPW];  // 39936 B

  int M = 0;
  for (int i = 0; i < B; ++i) M += (lengths[i] + (SW - 1)) >> 2;

  const int tid = threadIdx.x;
  const long long m0 = (long long)blockIdx.x * BM;
  const int wv = tid >> 6;       // 0..7 -> rows wv*16..wv*16+15
  const int lane = tid & 63;
  const int lm = lane & 15;
  const int quad = lane >> 4;

  // A-fragments: row = lm, k = quad*8 + ks*32 + j. Issued before the barrier.
  bf16x8 af[3];
  const short* arow = wsA + (m0 + wv * 16 + lm) * CIN;
  #pragma unroll
  for (int ks = 0; ks < 3; ++ks)
    af[ks] = *(const bf16x8*)(arow + ks * 32 + quad * 8);

  // Stage Wt -> LDS, linear float4 copy (39936 B = 2496 float4).
  const float4* src = (const float4*)wsWt;
  float4* dst = (float4*)Wt_lds;
  #pragma unroll
  for (int i = 0; i < 5; ++i) {
    const int idx = tid + TPB_B * i;
    if (idx < (COUT * KPW * 2 / 16)) dst[idx] = src[idx];
  }
  __syncthreads();

  f32x4 acc[12];
  #pragma unroll
  for (int nt = 0; nt < 12; ++nt) acc[nt] = (f32x4){0.f, 0.f, 0.f, 0.f};

  #pragma unroll
  for (int nt = 0; nt < 12; ++nt) {
    const int nrow = nt * 16 + lm;  // B-frag: col n = lane&15, k = quad*8+j
    #pragma unroll
    for (int ks = 0; ks < 3; ++ks) {
      bf16x8 bfr = *(const bf16x8*)&Wt_lds[nrow * KPW + ks * 32 + quad * 8];
      acc[nt] = __builtin_amdgcn_mfma_f32_16x16x32_bf16(af[ks], bfr, acc[nt], 0, 0, 0);
    }
  }

  // Epilogue: bias + ReLU. C/D layout: col = lane&15, row = quad*4 + reg.
  #pragma unroll
  for (int nt = 0; nt < 12; ++nt) {
    const int col = nt * 16 + lm;
    const float bv = bias[col];
    const long long rbase = m0 + wv * 16 + quad * 4;
    #pragma unroll
    for (int r = 0; r < 4; ++r) {
      const long long m = rbase + r;
      if (m < M) {
        const float x = acc[nt][r] + bv;
        out[m * COUT + col] = x > 0.f ? x : 0.f;
      }
    }
  }
}

// ---------------------------------------------------------------------------
// Fallback: the verified round-0 fused kernel (used only if ws is too small).
// ---------------------------------------------------------------------------
__global__ __launch_bounds__(256) void fused_kernel(
    const float* __restrict__ feat, const float* __restrict__ coord,
    const float* __restrict__ scores, const float* __restrict__ W,
    const float* __restrict__ bias, const int* __restrict__ lengths, int B,
    float* __restrict__ out) {
  __shared__ short A_lds[BM * KPA];
  __shared__ short Wt_lds[COUT * KPW];
  __shared__ int s_meta[BM];

  const int tid = threadIdx.x;
  const long long m0 = (long long)blockIdx.x * BM;

  long long M = 0;
  for (int i = 0; i < B; ++i) M += ((long long)lengths[i] + (SW - 1)) >> 2;

  long long startL = 0; int cntL = 0, bfL = 0;
  if (tid < BM) {
    long long m = m0 + tid;
    long long off = 0, woff = 0;
    for (int i = 0; i < B; ++i) {
      long long L = lengths[i];
      long long nw = (L + (SW - 1)) >> 2;
      if (m >= woff && m < woff + nw) {
        long long st = off + (m - woff) * SW;
        long long rem = off + L - st;
        startL = st;
        cntL = (int)(rem < (long long)SW ? rem : (long long)SW);
        bfL = i;
      }
      off += L; woff += nw;
    }
    s_meta[tid] = (int)startL | (cntL << 28);
  }
  __syncthreads();

  #pragma unroll 4
  for (int i = 0; i < 12; ++i) {
    int task = tid + 256 * i;
    int w = task / 24;
    int g = task - w * 24;
    int mv = s_meta[w];
    int cw = (int)((unsigned)mv >> 28);
    int st = mv & 0x0FFFFFFF;
    const float* fp = feat + (long long)st * CIN + g * 4;
    float sx = 0.f, sy = 0.f, sz = 0.f, sw2 = 0.f;
    for (int p = 0; p < cw; ++p) {
      float4 v = *(const float4*)(fp + p * CIN);
      sx += v.x; sy += v.y; sz += v.z; sw2 += v.w;
    }
    float inv = cw ? 1.0f / (float)cw : 0.f;
    short4 h;
    h.x = f2bf(sx * inv); h.y = f2bf(sy * inv);
    h.z = f2bf(sz * inv); h.w = f2bf(sw2 * inv);
    *(short4*)&A_lds[w * KPA + g * 4] = h;
  }

  #pragma unroll 3
  for (int i = 0; i < 9; ++i) {
    int task = tid + 256 * i;
    int kg = task / COUT;
    int n = task - kg * COUT;
    const float* wp = W + kg * 8 * COUT + n;
    bf16x8 hv;
    #pragma unroll
    for (int j = 0; j < 8; ++j) hv[j] = f2bf(wp[j * COUT]);
    *(bf16x8*)&Wt_lds[n * KPW + kg * 8] = hv;
  }

  if (tid < BM) {
    long long m = m0 + tid;
    if (m < M) {
      float cx = 0.f, cy = 0.f, cz = 0.f, ss = 0.f;
      const float* cp = coord + startL * 3;
      for (int p = 0; p < cntL; ++p) {
        cx += cp[p * 3 + 0]; cy += cp[p * 3 + 1]; cz += cp[p * 3 + 2];
        ss += scores[startL + p];
      }
      float inv = 1.0f / (float)cntL;
      long long o1 = M * (long long)COUT;
      long long o2 = o1 + M * 3;
      long long o3 = o2 + M;
      out[o1 + m * 3 + 0] = cx * inv;
      out[o1 + m * 3 + 1] = cy * inv;
      out[o1 + m * 3 + 2] = cz * inv;
      out[o2 + m] = (float)bfL;
      out[o3 + m] = ss * inv;
    }
  }
  if (blockIdx.x == 0 && tid == 0) {
    long long o4 = M * (long long)(COUT + 3 + 1 + 1);
    long long cum = 0;
    for (int i = 0; i < B; ++i) {
      long long nw = ((long long)lengths[i] + (SW - 1)) >> 2;
      out[o4 + i] = (float)nw;
      cum += nw;
      out[o4 + B + i] = (float)cum;
    }
  }

  __syncthreads();

  const int wv = tid >> 6;
  const int lane = tid & 63;
  const int lm = lane & 15;
  const int quad = lane >> 4;

  bf16x8 af[2][3];
  #pragma unroll
  for (int mt = 0; mt < 2; ++mt)
    #pragma unroll
    for (int ks = 0; ks < 3; ++ks)
      af[mt][ks] = *(const bf16x8*)&A_lds[(wv * 32 + mt * 16 + lm) * KPA + ks * 32 + quad * 8];

  f32x4 acc[2][12];
  #pragma unroll
  for (int mt = 0; mt < 2; ++mt)
    #pragma unroll
    for (int nt = 0; nt < 12; ++nt)
      acc[mt][nt] = (f32x4){0.f, 0.f, 0.f, 0.f};

  #pragma unroll
  for (int nt = 0; nt < 12; ++nt) {
    const int nrow = nt * 16 + lm;
    #pragma unroll
    for (int ks = 0; ks < 3; ++ks) {
      bf16x8 bfr = *(const bf16x8*)&Wt_lds[nrow * KPW + ks * 32 + quad * 8];
      acc[0][nt] = __builtin_amdgcn_mfma_f32_16x16x32_bf16(af[0][ks], bfr, acc[0][nt], 0, 0, 0);
      acc[1][nt] = __builtin_amdgcn_mfma_f32_16x16x32_bf16(af[1][ks], bfr, acc[1][nt], 0, 0, 0);
    }
  }

  #pragma unroll
  for (int nt = 0; nt < 12; ++nt) {
    int col = nt * 16 + lm;
    float bv = bias[col];
    #pragma unroll
    for (int mt = 0; mt < 2; ++mt) {
      long long rbase = m0 + wv * 32 + mt * 16 + quad * 4;
      #pragma unroll
      for (int r = 0; r < 4; ++r) {
        long long m = rbase + r;
        if (m < M) {
          float x = acc[mt][nt][r] + bv;
          out[m * COUT + col] = x > 0.f ? x : 0.f;
        }
      }
    }
  }
}

extern "C" void kernel_launch(void* const* d_in, const int* in_sizes, int n_in,
                              void* d_out, int out_size, void* d_ws, size_t ws_size,
                              hipStream_t stream) {
  const float* feat    = (const float*)d_in[0];
  const float* coord   = (const float*)d_in[1];
  const float* scores  = (const float*)d_in[2];
  const float* W       = (const float*)d_in[3];
  const float* bias    = (const float*)d_in[4];
  const int*   lengths = (const int*)d_in[5];
  float* out = (float*)d_out;

  const int N = in_sizes[2];   // number of points (scores is (N,))
  const int B = in_sizes[5];   // number of batches
  const int Mmax = N / SW + B; // data-independent upper bound on window count

  const int blocksB = (Mmax + BM - 1) / BM;
  const long long Mpad = (long long)blocksB * BM;
  const size_t A_bytes = (size_t)Mpad * CIN * sizeof(short);      // ~50.36 MB
  const size_t WT_bytes = (size_t)COUT * KPW * sizeof(short);     // 39936 B

  if (ws_size >= A_bytes + WT_bytes) {
    short* wsA = (short*)d_ws;
    short* wsWt = (short*)((char*)d_ws + A_bytes);
    const long long Tmax = (long long)Mmax * 25 + COUT * 12;
    const int blocksA = (int)((Tmax + (long long)TPB_A * TPT_A - 1) /
                              ((long long)TPB_A * TPT_A));
    pool_kernel<<<blocksA, TPB_A, 0, stream>>>(feat, coord, scores, W, lengths,
                                               B, wsA, wsWt, out);
    gemm_kernel<<<blocksB, TPB_B, 0, stream>>>(wsA, wsWt, bias, lengths, B, out);
  } else {
    fused_kernel<<<blocksB, 256, 0, stream>>>(feat, coord, scores, W, bias,
                                              lengths, B, out);
  }
}

// Round 4
// 639.537 us; speedup vs baseline: 1.1486x; 1.0192x over previous
//
#include <hip/hip_runtime.h>

#define CIN 96
#define COUT 192
#define SW 4
#define BM 128        // rows (windows) per GEMM block
#define KPA 96        // fallback A row stride (shorts)
#define KPW 104       // Wt row stride (shorts); 16B-multiple, conflict-light
#define TPB_A 256
#define TPB_B 512

typedef __attribute__((ext_vector_type(8))) short bf16x8;
typedef __attribute__((ext_vector_type(4))) float f32x4;

// fp32 -> bf16 round-to-nearest-even, bit pattern in a short
__device__ __forceinline__ short f2bf(float x) {
  unsigned int u;
  __builtin_memcpy(&u, &x, 4);
  u += 0x7fffu + ((u >> 16) & 1u);
  return (short)(u >> 16);
}

// ---------------------------------------------------------------------------
// Kernel A: pure streaming, ONE tiny task per thread (TLP over ILP: 25k
// blocks -> 32 resident waves/CU, each with 4 independent loads in flight).
// Task ranges (t = global thread id):
//   [0, M*24)        : pooled A. w = t/24, g = t%24: mean of 4 rows' float4
//                      group g -> bf16 short4 into wsA[w][g*4..+4).
//   [M*24, M*25)     : coord/scores/batch pooled outputs for window m.
//   [M*25, M*25+2304): W transpose -> bf16 Wt[n][k] (KPW-padded) into wsWt.
// Plus lengths_down/offset_down written by thread t==0.
// ---------------------------------------------------------------------------
__global__ __launch_bounds__(TPB_A) void pool_kernel(
    const float* __restrict__ feat, const float* __restrict__ coord,
    const float* __restrict__ scores, const float* __restrict__ W,
    const int* __restrict__ lengths, int B,
    short* __restrict__ wsA, short* __restrict__ wsWt,
    float* __restrict__ out) {
  int M = 0;
  for (int i = 0; i < B; ++i) M += (lengths[i] + (SW - 1)) >> 2;
  const int R0 = M * 24;
  const int R1 = R0 + M;
  const int R2 = R1 + COUT * 12;

  const int t = blockIdx.x * TPB_A + threadIdx.x;

  if (t < R0) {
    // ---- pooled A ----
    const int w = t / 24;
    const int g = t - w * 24;
    int off = 0, woff = 0, st = 0, cw = 0;
    for (int i = 0; i < B; ++i) {
      const int L = lengths[i];
      const int nw = (L + (SW - 1)) >> 2;
      if (w >= woff && w < woff + nw) {
        st = off + (w - woff) * SW;
        const int rem = off + L - st;
        cw = rem < SW ? rem : SW;
      }
      off += L; woff += nw;
    }
    const float* fp = feat + (long long)st * CIN + g * 4;
    // Unconditional 4-row load (always in-bounds: last window of last batch
    // is full), mask tail rows of short windows by multiply.
    float4 v0 = *(const float4*)(fp);
    float4 v1 = *(const float4*)(fp + CIN);
    float4 v2 = *(const float4*)(fp + 2 * CIN);
    float4 v3 = *(const float4*)(fp + 3 * CIN);
    const float k1 = (cw > 1) ? 1.f : 0.f;
    const float k2 = (cw > 2) ? 1.f : 0.f;
    const float k3 = (cw > 3) ? 1.f : 0.f;
    const float inv = 1.0f / (float)cw;
    short4 h;
    h.x = f2bf((v0.x + k1 * v1.x + k2 * v2.x + k3 * v3.x) * inv);
    h.y = f2bf((v0.y + k1 * v1.y + k2 * v2.y + k3 * v3.y) * inv);
    h.z = f2bf((v0.z + k1 * v1.z + k2 * v2.z + k3 * v3.z) * inv);
    h.w = f2bf((v0.w + k1 * v1.w + k2 * v2.w + k3 * v3.w) * inv);
    *(short4*)&wsA[(long long)w * CIN + g * 4] = h;
  } else if (t < R1) {
    // ---- coord / scores / batch pooled outputs ----
    const int m = t - R0;
    int off = 0, woff = 0, st = 0, cw = 0, bf = 0;
    for (int i = 0; i < B; ++i) {
      const int L = lengths[i];
      const int nw = (L + (SW - 1)) >> 2;
      if (m >= woff && m < woff + nw) {
        st = off + (m - woff) * SW;
        const int rem = off + L - st;
        cw = rem < SW ? rem : SW;
        bf = i;
      }
      off += L; woff += nw;
    }
    const float* cp = coord + (long long)st * 3;
    const float* sp = scores + st;
    float cx = 0.f, cy = 0.f, cz = 0.f, ss = 0.f;
    #pragma unroll
    for (int p = 0; p < 4; ++p) {
      const float mk = (p < cw) ? 1.f : 0.f;
      cx = fmaf(mk, cp[p * 3 + 0], cx);
      cy = fmaf(mk, cp[p * 3 + 1], cy);
      cz = fmaf(mk, cp[p * 3 + 2], cz);
      ss = fmaf(mk, sp[p], ss);
    }
    const float inv = 1.0f / (float)cw;
    const long long o1 = (long long)M * COUT;
    const long long o2 = o1 + (long long)M * 3;
    const long long o3 = o2 + M;
    out[o1 + (long long)m * 3 + 0] = cx * inv;
    out[o1 + (long long)m * 3 + 1] = cy * inv;
    out[o1 + (long long)m * 3 + 2] = cz * inv;
    out[o2 + m] = (float)bf;
    out[o3 + m] = ss * inv;
  } else if (t < R2) {
    // ---- W transpose -> bf16 Wt[n][k], KPW-padded rows ----
    const int j = t - R1;
    const int kg = j / COUT;
    const int n = j - kg * COUT;
    const float* wp = W + (long long)kg * 8 * COUT + n;
    bf16x8 hv;
    #pragma unroll
    for (int q = 0; q < 8; ++q) hv[q] = f2bf(wp[q * COUT]);
    *(bf16x8*)&wsWt[n * KPW + kg * 8] = hv;
  }

  if (t == 0) {
    const long long o4 = (long long)M * (COUT + 3 + 1 + 1);
    long long cum = 0;
    for (int i = 0; i < B; ++i) {
      const long long nw = ((long long)lengths[i] + (SW - 1)) >> 2;
      out[o4 + i] = (float)nw;
      cum += nw;
      out[o4 + B + i] = (float)cum;
    }
  }
}

// ---------------------------------------------------------------------------
// Kernel B: lean GEMM, swapped-operand MFMA for float4 stores.
// mfma(bfr, af): D[i=quad*4+reg][j=lane&15] with i <- Wt row (n), j <- A row
// (m). So each lane holds row m = lane&15, cols n = nt*16+quad*4+{0..3}
// -> epilogue is 12 global_store_dwordx4/wave with one row-bound check.
// ---------------------------------------------------------------------------
__global__ __launch_bounds__(TPB_B) void gemm_kernel(
    const short* __restrict__ wsA, const short* __restrict__ wsWt,
    const float* __restrict__ bias, const int* __restrict__ lengths, int B,
    float* __restrict__ out) {
  __shared__ alignas(16) short Wt_lds[COUT * KPW];  // 39936 B

  int M = 0;
  for (int i = 0; i < B; ++i) M += (lengths[i] + (SW - 1)) >> 2;

  const int tid = threadIdx.x;
  const long long m0 = (long long)blockIdx.x * BM;
  const int wv = tid >> 6;       // 0..7 -> rows wv*16..wv*16+15
  const int lane = tid & 63;
  const int lm = lane & 15;
  const int quad = lane >> 4;

  // A-fragments: row = lm, k = quad*8 + ks*32 + j. Issued before the barrier
  // so HBM latency hides under Wt staging.
  bf16x8 af[3];
  const short* arow = wsA + (m0 + wv * 16 + lm) * CIN;
  #pragma unroll
  for (int ks = 0; ks < 3; ++ks)
    af[ks] = *(const bf16x8*)(arow + ks * 32 + quad * 8);

  // Stage Wt -> LDS, linear float4 copy (39936 B = 2496 float4).
  const float4* src = (const float4*)wsWt;
  float4* dst = (float4*)Wt_lds;
  #pragma unroll
  for (int i = 0; i < 5; ++i) {
    const int idx = tid + TPB_B * i;
    if (idx < (COUT * KPW * 2 / 16)) dst[idx] = src[idx];
  }
  __syncthreads();

  f32x4 acc[12];
  #pragma unroll
  for (int nt = 0; nt < 12; ++nt) acc[nt] = (f32x4){0.f, 0.f, 0.f, 0.f};

  #pragma unroll
  for (int nt = 0; nt < 12; ++nt) {
    const int nrow = nt * 16 + lm;  // lanes hold Wt rows nt*16..+15
    #pragma unroll
    for (int ks = 0; ks < 3; ++ks) {
      bf16x8 bfr = *(const bf16x8*)&Wt_lds[nrow * KPW + ks * 32 + quad * 8];
      acc[nt] = __builtin_amdgcn_mfma_f32_16x16x32_bf16(bfr, af[ks], acc[nt], 0, 0, 0);
    }
  }

  // Epilogue: bias + ReLU, float4 stores. Lane's row m = m0+wv*16+lm.
  const long long m = m0 + wv * 16 + lm;
  if (m < M) {
    float* orow = out + m * COUT;
    #pragma unroll
    for (int nt = 0; nt < 12; ++nt) {
      const int c0 = nt * 16 + quad * 4;
      const float4 bv = *(const float4*)&bias[c0];
      float4 o;
      o.x = acc[nt][0] + bv.x; o.x = o.x > 0.f ? o.x : 0.f;
      o.y = acc[nt][1] + bv.y; o.y = o.y > 0.f ? o.y : 0.f;
      o.z = acc[nt][2] + bv.z; o.z = o.z > 0.f ? o.z : 0.f;
      o.w = acc[nt][3] + bv.w; o.w = o.w > 0.f ? o.w : 0.f;
      *(float4*)&orow[c0] = o;
    }
  }
}

// ---------------------------------------------------------------------------
// Fallback: the verified round-0 fused kernel (used only if ws is too small).
// ---------------------------------------------------------------------------
__global__ __launch_bounds__(256) void fused_kernel(
    const float* __restrict__ feat, const float* __restrict__ coord,
    const float* __restrict__ scores, const float* __restrict__ W,
    const float* __restrict__ bias, const int* __restrict__ lengths, int B,
    float* __restrict__ out) {
  __shared__ short A_lds[BM * KPA];
  __shared__ short Wt_lds[COUT * KPW];
  __shared__ int s_meta[BM];

  const int tid = threadIdx.x;
  const long long m0 = (long long)blockIdx.x * BM;

  long long M = 0;
  for (int i = 0; i < B; ++i) M += ((long long)lengths[i] + (SW - 1)) >> 2;

  long long startL = 0; int cntL = 0, bfL = 0;
  if (tid < BM) {
    long long m = m0 + tid;
    long long off = 0, woff = 0;
    for (int i = 0; i < B; ++i) {
      long long L = lengths[i];
      long long nw = (L + (SW - 1)) >> 2;
      if (m >= woff && m < woff + nw) {
        long long st = off + (m - woff) * SW;
        long long rem = off + L - st;
        startL = st;
        cntL = (int)(rem < (long long)SW ? rem : (long long)SW);
        bfL = i;
      }
      off += L; woff += nw;
    }
    s_meta[tid] = (int)startL | (cntL << 28);
  }
  __syncthreads();

  #pragma unroll 4
  for (int i = 0; i < 12; ++i) {
    int task = tid + 256 * i;
    int w = task / 24;
    int g = task - w * 24;
    int mv = s_meta[w];
    int cw = (int)((unsigned)mv >> 28);
    int st = mv & 0x0FFFFFFF;
    const float* fp = feat + (long long)st * CIN + g * 4;
    float sx = 0.f, sy = 0.f, sz = 0.f, sw2 = 0.f;
    for (int p = 0; p < cw; ++p) {
      float4 v = *(const float4*)(fp + p * CIN);
      sx += v.x; sy += v.y; sz += v.z; sw2 += v.w;
    }
    float inv = cw ? 1.0f / (float)cw : 0.f;
    short4 h;
    h.x = f2bf(sx * inv); h.y = f2bf(sy * inv);
    h.z = f2bf(sz * inv); h.w = f2bf(sw2 * inv);
    *(short4*)&A_lds[w * KPA + g * 4] = h;
  }

  #pragma unroll 3
  for (int i = 0; i < 9; ++i) {
    int task = tid + 256 * i;
    int kg = task / COUT;
    int n = task - kg * COUT;
    const float* wp = W + kg * 8 * COUT + n;
    bf16x8 hv;
    #pragma unroll
    for (int j = 0; j < 8; ++j) hv[j] = f2bf(wp[j * COUT]);
    *(bf16x8*)&Wt_lds[n * KPW + kg * 8] = hv;
  }

  if (tid < BM) {
    long long m = m0 + tid;
    if (m < M) {
      float cx = 0.f, cy = 0.f, cz = 0.f, ss = 0.f;
      const float* cp = coord + startL * 3;
      for (int p = 0; p < cntL; ++p) {
        cx += cp[p * 3 + 0]; cy += cp[p * 3 + 1]; cz += cp[p * 3 + 2];
        ss += scores[startL + p];
      }
      float inv = 1.0f / (float)cntL;
      long long o1 = M * (long long)COUT;
      long long o2 = o1 + M * 3;
      long long o3 = o2 + M;
      out[o1 + m * 3 + 0] = cx * inv;
      out[o1 + m * 3 + 1] = cy * inv;
      out[o1 + m * 3 + 2] = cz * inv;
      out[o2 + m] = (float)bfL;
      out[o3 + m] = ss * inv;
    }
  }
  if (blockIdx.x == 0 && tid == 0) {
    long long o4 = M * (long long)(COUT + 3 + 1 + 1);
    long long cum = 0;
    for (int i = 0; i < B; ++i) {
      long long nw = ((long long)lengths[i] + (SW - 1)) >> 2;
      out[o4 + i] = (float)nw;
      cum += nw;
      out[o4 + B + i] = (float)cum;
    }
  }

  __syncthreads();

  const int wv = tid >> 6;
  const int lane = tid & 63;
  const int lm = lane & 15;
  const int quad = lane >> 4;

  bf16x8 af[2][3];
  #pragma unroll
  for (int mt = 0; mt < 2; ++mt)
    #pragma unroll
    for (int ks = 0; ks < 3; ++ks)
      af[mt][ks] = *(const bf16x8*)&A_lds[(wv * 32 + mt * 16 + lm) * KPA + ks * 32 + quad * 8];

  f32x4 acc[2][12];
  #pragma unroll
  for (int mt = 0; mt < 2; ++mt)
    #pragma unroll
    for (int nt = 0; nt < 12; ++nt)
      acc[mt][nt] = (f32x4){0.f, 0.f, 0.f, 0.f};

  #pragma unroll
  for (int nt = 0; nt < 12; ++nt) {
    const int nrow = nt * 16 + lm;
    #pragma unroll
    for (int ks = 0; ks < 3; ++ks) {
      bf16x8 bfr = *(const bf16x8*)&Wt_lds[nrow * KPW + ks * 32 + quad * 8];
      acc[0][nt] = __builtin_amdgcn_mfma_f32_16x16x32_bf16(af[0][ks], bfr, acc[0][nt], 0, 0, 0);
      acc[1][nt] = __builtin_amdgcn_mfma_f32_16x16x32_bf16(af[1][ks], bfr, acc[1][nt], 0, 0, 0);
    }
  }

  #pragma unroll
  for (int nt = 0; nt < 12; ++nt) {
    int col = nt * 16 + lm;
    float bv = bias[col];
    #pragma unroll
    for (int mt = 0; mt < 2; ++mt) {
      long long rbase = m0 + wv * 32 + mt * 16 + quad * 4;
      #pragma unroll
      for (int r = 0; r < 4; ++r) {
        long long m = rbase + r;
        if (m < M) {
          float x = acc[mt][nt][r] + bv;
          out[m * COUT + col] = x > 0.f ? x : 0.f;
        }
      }
    }
  }
}

extern "C" void kernel_launch(void* const* d_in, const int* in_sizes, int n_in,
                              void* d_out, int out_size, void* d_ws, size_t ws_size,
                              hipStream_t stream) {
  const float* feat    = (const float*)d_in[0];
  const float* coord   = (const float*)d_in[1];
  const float* scores  = (const float*)d_in[2];
  const float* W       = (const float*)d_in[3];
  const float* bias    = (const float*)d_in[4];
  const int*   lengths = (const int*)d_in[5];
  float* out = (float*)d_out;

  const int N = in_sizes[2];   // number of points (scores is (N,))
  const int B = in_sizes[5];   // number of batches
  const int Mmax = N / SW + B; // data-independent upper bound on window count

  const int blocksB = (Mmax + BM - 1) / BM;
  const long long Mpad = (long long)blocksB * BM;
  const size_t A_bytes = (size_t)Mpad * CIN * sizeof(short);      // ~50.36 MB
  const size_t WT_bytes = (size_t)COUT * KPW * sizeof(short);     // 39936 B

  if (ws_size >= A_bytes + WT_bytes) {
    short* wsA = (short*)d_ws;
    short* wsWt = (short*)((char*)d_ws + A_bytes);
    const long long Tmax = (long long)Mmax * 25 + COUT * 12;
    const int blocksA = (int)((Tmax + TPB_A - 1) / TPB_A);
    pool_kernel<<<blocksA, TPB_A, 0, stream>>>(feat, coord, scores, W, lengths,
                                               B, wsA, wsWt, out);
    gemm_kernel<<<blocksB, TPB_B, 0, stream>>>(wsA, wsWt, bias, lengths, B, out);
  } else {
    fused_kernel<<<blocksB, 256, 0, stream>>>(feat, coord, scores, W, bias,
                                              lengths, B, out);
  }
}